// Round 16
// baseline (114.407 us; speedup 1.0000x reference)
//
#include <hip/hip_runtime.h>

#define NLAT 192
#define NPTS 40320
#define MMAX 96
#define LMAX 96
#define NV   100
#define MAXN 400
#define NB   400   // total B rows = 4 * NV

typedef __attribute__((ext_vector_type(8))) _Float16 half8v;  // 8 f16 (4 VGPRs)
typedef __attribute__((ext_vector_type(4))) float f32x4;

static __device__ __forceinline__ float bits2f(unsigned int b) {
    union { unsigned int i; float f; } v; v.i = b; return v.f;
}
static __device__ __forceinline__ unsigned int f2bf(float f) {
    union { float f; unsigned int i; } v; v.f = f;
    return (v.i + 0x7FFFu + ((v.i >> 16) & 1u)) >> 16;
}
static __device__ __forceinline__ unsigned short f2h(float f) {
    union { _Float16 h; unsigned short s; } u; u.h = (_Float16)f; return u.s;
}
static __device__ __forceinline__ float h2f(unsigned short s) {
    union { _Float16 h; unsigned short s; } u; u.s = s; return (float)u.h;
}
// split f32 pair -> hi f16 pair (RTZ, packed) + lo f16 pair (residual)
static __device__ __forceinline__ void split2(float a, float b,
                                              unsigned int& hw, unsigned int& lw) {
    auto hv = __builtin_amdgcn_cvt_pkrtz(a, b);            // v_cvt_pkrtz_f16_f32
    float ra = a - (float)hv[0], rb = b - (float)hv[1];
    auto lv = __builtin_amdgcn_cvt_pkrtz(ra, rb);
    union { decltype(hv) v; unsigned int u; } uh, ul;
    uh.v = hv; ul.v = lv;
    hw = uh.u; lw = ul.u;
}

// S(n) = sum_{t<n} floor(t/8)
static __device__ __forceinline__ int Ssum(int n) {
    int q = n >> 3, r = n & 7; return 4 * q * (q - 1) + q * r;
}
// padded-32 k-units before ring j in At (ragged layout); total = 43008
static __device__ __forceinline__ int atoffk(int j) {
    if (j < 96) return 32 * (Ssum(j + 12) - 4);
    return 32 * (672 + 676 - Ssum(204 - j));
}
static __device__ __forceinline__ int kpad_of(int j) {
    return 32 * ((j < 96 ? (j + 12) : (203 - j)) >> 3);
}

// ---------------- K0a: split leg fp32 -> f16 hi/lo, relayout [l][m][j] -> [m][l][j]
__global__ __launch_bounds__(256) void leg_conv_kernel(
    const float* __restrict__ leg,    // [96 l][96 m][192 j]
    unsigned short* __restrict__ legh,
    unsigned short* __restrict__ legl)
{
    int idx = blockIdx.x * 256 + threadIdx.x;
    if (idx >= 96 * 96 * 192) return;
    int j = idx % 192;
    int lm = idx / 192;
    int m = lm % 96, l = lm / 96;
    float v = leg[idx];
    unsigned short h = f2h(v);
    unsigned short lo = f2h(v - h2f(h));
    size_t o = ((size_t)m * 96 + l) * 192 + j;
    legh[o] = h;
    legl[o] = lo;
}

// ---------------- K0b: transpose dft words into At (f16), k-step-blocked:
// At[j]: per k-step t, contiguous [192 rows][32 k] f16 (12288 B)
__global__ __launch_bounds__(256) void dft_transpose_kernel(
    const unsigned int* __restrict__ dftw,   // [192][400][96] (bf16 re | im<<16)
    unsigned short* __restrict__ At)
{
    const int j = blockIdx.x;
    const int kpad = kpad_of(j);
    const int t = blockIdx.y;
    const int k0 = t * 32;
    if (k0 >= kpad) return;
    const int n = j < 96 ? 20 + 4 * j : 400 - 4 * (j - 96);
    unsigned short* abase = At + (size_t)atoffk(j) * 192 + (size_t)t * 6144;
    const int tid = threadIdx.x;
#pragma unroll
    for (int s = 0; s < 3; ++s) {
        int slot = s * 256 + tid;          // 768 = 192 rows x 4 chunks
        int row = slot % 192;
        int ch  = slot / 192;
        int m = row < 96 ? row : row - 96;
        bool isIm = row >= 96;
        const unsigned int* dp = dftw + ((size_t)j * MAXN + k0 + ch * 8) * 96 + m;
        unsigned short o[8];
#pragma unroll
        for (int i = 0; i < 8; ++i) {
            int k = k0 + ch * 8 + i;
            unsigned int v = (k < n) ? dp[(size_t)i * 96] : 0u;
            float f = isIm ? bits2f(v & 0xFFFF0000u) : bits2f(v << 16);
            o[i] = f2h(f);
        }
        uint4 pk;
        pk.x = (unsigned int)o[0] | ((unsigned int)o[1] << 16);
        pk.y = (unsigned int)o[2] | ((unsigned int)o[3] << 16);
        pk.z = (unsigned int)o[4] | ((unsigned int)o[5] << 16);
        pk.w = (unsigned int)o[6] | ((unsigned int)o[7] << 16);
        *(uint4*)(abase + (size_t)row * 32 + ch * 8) = pk;
    }
}

// ---------------- K1 (MFMA f16): ring DFT GEMM — no LDS/barriers, max TLP,
// STATIC register double-buffer (rule #20: no runtime-indexed private arrays).
// Wave = (ring-pair pp, m-half mh, 16-col tile ct). Grid = 48 duos x 25 tiles.
__global__ __launch_bounds__(256, 4) void dft_mfma_kernel(
    const float* __restrict__ data,          // [4][NPTS][NV] fp32
    const unsigned short* __restrict__ At,   // ragged [j][t][192][32] f16
    unsigned short* __restrict__ fh)         // [NLAT][192][NB] f16
{
    const int id  = blockIdx.x;
    const int pg  = id % 48;                 // pair-duo (same-XCD At reuse)
    const int ct  = id / 48;                 // col tile 0..24
    const int tid = threadIdx.x;
    const int w   = tid >> 6;
    const int l   = tid & 63;
    const int lr  = l & 15;
    const int kg  = l >> 4;
    const int pp  = 2 * pg + (w >> 1);       // ring pair 0..95
    const int mh  = w & 1;                   // m-half: 0 = re rows, 1 = im rows

    const int Bb = ct * 16 + lr;             // global B col 0..399
    const int bb = Bb / NV, vv = Bb % NV;
    const float* dbase = data + (size_t)bb * NPTS * NV + vv;

    for (int rr = 0; rr < 2; ++rr) {
        int j, n, start;
        if (rr == 0) { j = pp;      n = 20 + 4 * pp;  start = 2 * pp * pp + 18 * pp; }
        else         { j = 96 + pp; n = 400 - 4 * pp; start = 20160 + 402 * pp - 2 * pp * pp; }
        const int nsteps = kpad_of(j) >> 5;

        // rolling A pointer: this thread's fragment base for step 0
        const unsigned short* ap = At + (size_t)atoffk(j) * 192
                                 + (size_t)(mh * 96 + lr) * 32 + kg * 8;
        // X: per-lane step-0 base; xpf = prefetch pointer (step 2 onward)
        const float* xl  = dbase + (size_t)(start + kg * 8) * NV;
        const float* xpf = xl + (size_t)64 * NV;

        f32x4 acc[6];
#pragma unroll
        for (int mt = 0; mt < 6; ++mt) acc[mt] = (f32x4){0.f, 0.f, 0.f, 0.f};

        float x0[8], x1[8];

        auto pre_fast = [&](float (&xb)[8]) {
#pragma unroll
            for (int i = 0; i < 8; ++i) xb[i] = xpf[(size_t)i * NV];  // imm offsets
            xpf += (size_t)32 * NV;
        };
        auto pre_clamp = [&](float (&xb)[8], int tt) {
#pragma unroll
            for (int i = 0; i < 8; ++i) {
                int k = tt * 32 + kg * 8 + i; if (k > n - 1) k = n - 1;
                xb[i] = dbase[(size_t)(start + k) * NV];
            }
        };
        auto stepf = [&](float (&xb)[8], int t) {
            // convert X(t) -> hi/lo packed fragments
            unsigned int BH[4], BL[4];
#pragma unroll
            for (int q = 0; q < 4; ++q)
                split2(xb[2 * q], xb[2 * q + 1], BH[q], BL[q]);
            // prefetch X(t+2) into the buffer just consumed
            int tt = t + 2;
            if (tt < nsteps) {
                if (tt < nsteps - 1) pre_fast(xb);
                else pre_clamp(xb, tt);
            }
            union { uint4 u; half8v h; } ubh, ubl;
            ubh.u = (uint4){BH[0], BH[1], BH[2], BH[3]};
            ubl.u = (uint4){BL[0], BL[1], BL[2], BL[3]};
            const unsigned short* a = ap;
#pragma unroll
            for (int mt = 0; mt < 6; ++mt) {
                half8v av = *(const half8v*)(a + mt * 512);
                acc[mt] = __builtin_amdgcn_mfma_f32_16x16x32_f16(av, ubh.h, acc[mt], 0, 0, 0);
                acc[mt] = __builtin_amdgcn_mfma_f32_16x16x32_f16(av, ubl.h, acc[mt], 0, 0, 0);
            }
            ap += 6144;
        };

        // prologue: X(0), X(1)
        if (nsteps == 1) {
            pre_clamp(x0, 0);
        } else {
#pragma unroll
            for (int i = 0; i < 8; ++i) x0[i] = xl[(size_t)i * NV];
            if (nsteps == 2) pre_clamp(x1, 1);
            else {
#pragma unroll
                for (int i = 0; i < 8; ++i) x1[i] = xl[(size_t)(32 + i) * NV];
            }
        }

        int t = 0;
        while (true) {
            stepf(x0, t); if (++t >= nsteps) break;
            stepf(x1, t); if (++t >= nsteps) break;
        }

        // epilogue: C/D col=lane&15 (B), row=(lane>>4)*4+reg; emit f16
#pragma unroll
        for (int mt = 0; mt < 6; ++mt) {
#pragma unroll
            for (int r = 0; r < 4; ++r)
                fh[((size_t)j * 192 + mh * 96 + mt * 16 + kg * 4 + r) * NB + Bb] =
                    f2h(acc[mt][r]);
        }
    }
}

// ---------------- K2 (MFMA f16): Legendre contraction — no LDS/barriers,
// F register double-buffered (static two-call alternation).
static __device__ __forceinline__ void k2_step(
    unsigned short (&fcur)[2][8], unsigned short (&fnxt)[2][8],
    f32x4 (&acc)[6][2], int s, int m, int lr, int kg, int col,
    const unsigned short* __restrict__ legh,
    const unsigned short* __restrict__ legl,
    const unsigned short* __restrict__ fh)
{
    const int j0 = s * 32;
    half8v ah[6], al[6];
#pragma unroll
    for (int lt = 0; lt < 6; ++lt) {
        size_t o = ((size_t)m * 96 + lt * 16 + lr) * 192 + j0 + kg * 8;
        ah[lt] = *(const half8v*)&legh[o];
        al[lt] = *(const half8v*)&legl[o];
    }
    if (s + 1 < 6) {
        const int jn = (s + 1) * 32 + kg * 8;
#pragma unroll
        for (int pl = 0; pl < 2; ++pl)
#pragma unroll
            for (int i = 0; i < 8; ++i)
                fnxt[pl][i] = fh[((size_t)(jn + i) * 192 + m + 96 * pl) * NB + col];
    }
    half8v fF[2];
#pragma unroll
    for (int pl = 0; pl < 2; ++pl) {
        union { half8v h; unsigned short s16[8]; } uf;
#pragma unroll
        for (int i = 0; i < 8; ++i) uf.s16[i] = fcur[pl][i];
        fF[pl] = uf.h;
    }
#pragma unroll
    for (int lt = 0; lt < 6; ++lt)
#pragma unroll
        for (int pl = 0; pl < 2; ++pl) {
            acc[lt][pl] = __builtin_amdgcn_mfma_f32_16x16x32_f16(ah[lt], fF[pl], acc[lt][pl], 0, 0, 0);
            acc[lt][pl] = __builtin_amdgcn_mfma_f32_16x16x32_f16(al[lt], fF[pl], acc[lt][pl], 0, 0, 0);
        }
}

__global__ __launch_bounds__(256) void leg_mfma_kernel(
    const unsigned short* __restrict__ legh,  // [96 m][96 l][192 j] f16
    const unsigned short* __restrict__ legl,
    const unsigned short* __restrict__ fh,    // [192 j][192 mm][NB] f16
    unsigned int* __restrict__ out)           // [4][LMAX][MMAX][NV] packed bf16
{
    const int m   = blockIdx.x;
    const int bt  = blockIdx.y;
    const int tid = threadIdx.x;
    const int w   = tid >> 6;
    const int l   = tid & 63;
    const int lr  = l & 15;
    const int kg  = l >> 4;

    const int c  = w * 16 + lr;
    const bool cok = c < 50;
    const int col = bt * 50 + (cok ? c : 0);

    f32x4 acc[6][2];
#pragma unroll
    for (int lt = 0; lt < 6; ++lt)
#pragma unroll
        for (int pl = 0; pl < 2; ++pl) acc[lt][pl] = (f32x4){0.f, 0.f, 0.f, 0.f};

    unsigned short fA[2][8], fB[2][8];
#pragma unroll
    for (int pl = 0; pl < 2; ++pl)
#pragma unroll
        for (int i = 0; i < 8; ++i)
            fA[pl][i] = fh[((size_t)(kg * 8 + i) * 192 + m + 96 * pl) * NB + col];

#pragma unroll
    for (int ss = 0; ss < 3; ++ss) {
        k2_step(fA, fB, acc, 2 * ss,     m, lr, kg, col, legh, legl, fh);
        k2_step(fB, fA, acc, 2 * ss + 1, m, lr, kg, col, legh, legl, fh);
    }

    if (cok) {
        int B = bt * 50 + c;
        int bb = B / NV, vv = B % NV;
#pragma unroll
        for (int lt = 0; lt < 6; ++lt) {
#pragma unroll
            for (int r = 0; r < 4; ++r) {
                int ll = lt * 16 + kg * 4 + r;
                out[(((size_t)bb * LMAX + ll) * MMAX + m) * NV + vv] =
                    f2bf(acc[lt][0][r]) | (f2bf(acc[lt][1][r]) << 16);
            }
        }
    }
}

extern "C" void kernel_launch(void* const* d_in, const int* in_sizes, int n_in,
                              void* d_out, int out_size, void* d_ws, size_t ws_size,
                              hipStream_t stream) {
    if (n_in != 3) return;

    const float* data = (const float*)d_in[0];
    const unsigned int* dftw = (const unsigned int*)d_in[1];
    const float* leg  = (const float*)d_in[2];
    unsigned int* out = (unsigned int*)d_out;

    // ws: [legh][legl][At][fh]  (~53 MB total)
    const size_t LEGN = (size_t)96 * 96 * 192;
    const size_t LEGB = 2 * LEGN * sizeof(unsigned short);   // 7.08 MB
    const size_t ATN  = (size_t)43008 * 192;                 // shorts
    const size_t ATB  = ATN * sizeof(unsigned short);        // 16.5 MB
    const size_t FHB  = (size_t)192 * 192 * NB * sizeof(unsigned short); // 29.5 MB
    if (ws_size < LEGB + ATB + FHB) return;

    unsigned short* legh = (unsigned short*)d_ws;
    unsigned short* legl = legh + LEGN;
    unsigned short* At   = legl + LEGN;
    unsigned short* fh   = At + ATN;

    leg_conv_kernel<<<dim3((96 * 96 * 192 + 255) / 256), dim3(256), 0, stream>>>(
        leg, legh, legl);
    dft_transpose_kernel<<<dim3(192, 13), dim3(256), 0, stream>>>(dftw, At);

    dft_mfma_kernel<<<dim3(1200), dim3(256), 0, stream>>>(data, At, fh);
    leg_mfma_kernel<<<dim3(96, 8), dim3(256), 0, stream>>>(legh, legl, fh, out);
}

// Round 17
// 110.255 us; speedup vs baseline: 1.0377x; 1.0377x over previous
//
#include <hip/hip_runtime.h>

#define NLAT 192
#define NPTS 40320
#define MMAX 96
#define LMAX 96
#define NV   100
#define MAXN 400
#define NB   400   // total B rows = 4 * NV

typedef __attribute__((ext_vector_type(8))) _Float16 half8v;  // 8 f16 (4 VGPRs)
typedef __attribute__((ext_vector_type(4))) float f32x4;

static __device__ __forceinline__ float bits2f(unsigned int b) {
    union { unsigned int i; float f; } v; v.i = b; return v.f;
}
static __device__ __forceinline__ unsigned int f2bf(float f) {
    union { float f; unsigned int i; } v; v.f = f;
    return (v.i + 0x7FFFu + ((v.i >> 16) & 1u)) >> 16;
}
static __device__ __forceinline__ unsigned short f2h(float f) {
    union { _Float16 h; unsigned short s; } u; u.h = (_Float16)f; return u.s;
}
static __device__ __forceinline__ float h2f(unsigned short s) {
    union { _Float16 h; unsigned short s; } u; u.s = s; return (float)u.h;
}
// split f32 pair -> hi f16 pair (RTZ, packed) + lo f16 pair (residual)
static __device__ __forceinline__ void split2(float a, float b,
                                              unsigned int& hw, unsigned int& lw) {
    auto hv = __builtin_amdgcn_cvt_pkrtz(a, b);            // v_cvt_pkrtz_f16_f32
    float ra = a - (float)hv[0], rb = b - (float)hv[1];
    auto lv = __builtin_amdgcn_cvt_pkrtz(ra, rb);
    union { decltype(hv) v; unsigned int u; } uh, ul;
    uh.v = hv; ul.v = lv;
    hw = uh.u; lw = ul.u;
}

// S(n) = sum_{t<n} floor(t/8)
static __device__ __forceinline__ int Ssum(int n) {
    int q = n >> 3, r = n & 7; return 4 * q * (q - 1) + q * r;
}
// padded-32 k-units before ring j in At (ragged layout); total = 43008
static __device__ __forceinline__ int atoffk(int j) {
    if (j < 96) return 32 * (Ssum(j + 12) - 4);
    return 32 * (672 + 676 - Ssum(204 - j));
}
static __device__ __forceinline__ int kpad_of(int j) {
    return 32 * ((j < 96 ? (j + 12) : (203 - j)) >> 3);
}

// ---------------- K0a: split leg fp32 -> f16 hi/lo, relayout [l][m][j] -> [m][l][j]
__global__ __launch_bounds__(256) void leg_conv_kernel(
    const float* __restrict__ leg,    // [96 l][96 m][192 j]
    unsigned short* __restrict__ legh,
    unsigned short* __restrict__ legl)
{
    int idx = blockIdx.x * 256 + threadIdx.x;
    if (idx >= 96 * 96 * 192) return;
    int j = idx % 192;
    int lm = idx / 192;
    int m = lm % 96, l = lm / 96;
    float v = leg[idx];
    unsigned short h = f2h(v);
    unsigned short lo = f2h(v - h2f(h));
    size_t o = ((size_t)m * 96 + l) * 192 + j;
    legh[o] = h;
    legl[o] = lo;
}

// ---------------- K0b: transpose dft words into At (f16), k-step-blocked:
// At[j]: per k-step t, contiguous [192 rows][32 k] f16 (12288 B)
__global__ __launch_bounds__(256) void dft_transpose_kernel(
    const unsigned int* __restrict__ dftw,   // [192][400][96] (bf16 re | im<<16)
    unsigned short* __restrict__ At)
{
    const int j = blockIdx.x;
    const int kpad = kpad_of(j);
    const int t = blockIdx.y;
    const int k0 = t * 32;
    if (k0 >= kpad) return;
    const int n = j < 96 ? 20 + 4 * j : 400 - 4 * (j - 96);
    unsigned short* abase = At + (size_t)atoffk(j) * 192 + (size_t)t * 6144;
    const int tid = threadIdx.x;
#pragma unroll
    for (int s = 0; s < 3; ++s) {
        int slot = s * 256 + tid;          // 768 = 192 rows x 4 chunks
        int row = slot % 192;
        int ch  = slot / 192;
        int m = row < 96 ? row : row - 96;
        bool isIm = row >= 96;
        const unsigned int* dp = dftw + ((size_t)j * MAXN + k0 + ch * 8) * 96 + m;
        unsigned short o[8];
#pragma unroll
        for (int i = 0; i < 8; ++i) {
            int k = k0 + ch * 8 + i;
            unsigned int v = (k < n) ? dp[(size_t)i * 96] : 0u;
            float f = isIm ? bits2f(v & 0xFFFF0000u) : bits2f(v << 16);
            o[i] = f2h(f);
        }
        uint4 pk;
        pk.x = (unsigned int)o[0] | ((unsigned int)o[1] << 16);
        pk.y = (unsigned int)o[2] | ((unsigned int)o[3] << 16);
        pk.z = (unsigned int)o[4] | ((unsigned int)o[5] << 16);
        pk.w = (unsigned int)o[6] | ((unsigned int)o[7] << 16);
        *(uint4*)(abase + (size_t)row * 32 + ch * 8) = pk;
    }
}

// ---------------- K1 (MFMA f16): ring DFT GEMM — no LDS/barriers, 8 waves/SIMD.
// Wave = m-quarter mq (3 m-tiles, rows mq*48..mq*48+47) of block (pair p,
// col-tile ct). Grid = 96 pairs x 25 tiles = 2400 blocks / 9600 waves
// (9.4/SIMD available); __launch_bounds__(256,8) pins VGPR <= 64 so 8 are
// resident. A-loads at-use (TLP hides L2); X 2-deep static register prefetch.
__global__ __launch_bounds__(256, 8) void dft_mfma_kernel(
    const float* __restrict__ data,          // [4][NPTS][NV] fp32
    const unsigned short* __restrict__ At,   // ragged [j][t][192][32] f16
    unsigned short* __restrict__ fh)         // [NLAT][192][NB] f16
{
    const int id  = blockIdx.x;
    const int p   = id % 96;                 // ring pair (same-p -> same XCD)
    const int ct  = id / 96;                 // col tile 0..24
    const int tid = threadIdx.x;
    const int mq  = tid >> 6;                // m-quarter 0..3
    const int l   = tid & 63;
    const int lr  = l & 15;
    const int kg  = l >> 4;

    const int Bb = ct * 16 + lr;             // global B col 0..399
    const int bb = Bb / NV, vv = Bb % NV;
    const float* dbase = data + (size_t)bb * NPTS * NV + vv;

    for (int rr = 0; rr < 2; ++rr) {
        int j, n, start;
        if (rr == 0) { j = p;      n = 20 + 4 * p;  start = 2 * p * p + 18 * p; }
        else         { j = 96 + p; n = 400 - 4 * p; start = 20160 + 402 * p - 2 * p * p; }
        const int nsteps = kpad_of(j) >> 5;

        // rolling A pointer: this wave's 3-m-tile fragment base for step 0
        const unsigned short* ap = At + (size_t)atoffk(j) * 192
                                 + (size_t)(mq * 48 + lr) * 32 + kg * 8;
        const float* xl  = dbase + (size_t)(start + kg * 8) * NV;
        const float* xpf = xl + (size_t)64 * NV;

        f32x4 acc[3];
#pragma unroll
        for (int mt = 0; mt < 3; ++mt) acc[mt] = (f32x4){0.f, 0.f, 0.f, 0.f};

        float x0[8], x1[8];

        auto pre_fast = [&](float (&xb)[8]) {
#pragma unroll
            for (int i = 0; i < 8; ++i) xb[i] = xpf[(size_t)i * NV];  // imm offsets
            xpf += (size_t)32 * NV;
        };
        auto pre_clamp = [&](float (&xb)[8], int tt) {
#pragma unroll
            for (int i = 0; i < 8; ++i) {
                int k = tt * 32 + kg * 8 + i; if (k > n - 1) k = n - 1;
                xb[i] = dbase[(size_t)(start + k) * NV];
            }
        };
        auto stepf = [&](float (&xb)[8], int t) {
            unsigned int BH[4], BL[4];
#pragma unroll
            for (int q = 0; q < 4; ++q)
                split2(xb[2 * q], xb[2 * q + 1], BH[q], BL[q]);
            int tt = t + 2;                    // prefetch X(t+2)
            if (tt < nsteps) {
                if (tt < nsteps - 1) pre_fast(xb);
                else pre_clamp(xb, tt);
            }
            union { uint4 u; half8v h; } ubh, ubl;
            ubh.u = (uint4){BH[0], BH[1], BH[2], BH[3]};
            ubl.u = (uint4){BL[0], BL[1], BL[2], BL[3]};
            const unsigned short* a = ap;
#pragma unroll
            for (int mt = 0; mt < 3; ++mt) {
                half8v av = *(const half8v*)(a + mt * 512);   // 16 rows x 32 shorts
                acc[mt] = __builtin_amdgcn_mfma_f32_16x16x32_f16(av, ubh.h, acc[mt], 0, 0, 0);
                acc[mt] = __builtin_amdgcn_mfma_f32_16x16x32_f16(av, ubl.h, acc[mt], 0, 0, 0);
            }
            ap += 6144;
        };

        // prologue: X(0), X(1) (steps provably in-range except clamped cases)
        if (nsteps == 1) {
            pre_clamp(x0, 0);
        } else {
#pragma unroll
            for (int i = 0; i < 8; ++i) x0[i] = xl[(size_t)i * NV];
            if (nsteps == 2) pre_clamp(x1, 1);
            else {
#pragma unroll
                for (int i = 0; i < 8; ++i) x1[i] = xl[(size_t)(32 + i) * NV];
            }
        }

        int t = 0;
        while (true) {
            stepf(x0, t); if (++t >= nsteps) break;
            stepf(x1, t); if (++t >= nsteps) break;
        }

        // epilogue: C/D col=lane&15 (B), row=(lane>>4)*4+reg; emit f16
#pragma unroll
        for (int mt = 0; mt < 3; ++mt) {
#pragma unroll
            for (int r = 0; r < 4; ++r)
                fh[((size_t)j * 192 + mq * 48 + mt * 16 + kg * 4 + r) * NB + Bb] =
                    f2h(acc[mt][r]);
        }
    }
}

// ---------------- K2 (MFMA f16): Legendre contraction — no LDS/barriers,
// F register double-buffered (static two-call alternation).
static __device__ __forceinline__ void k2_step(
    unsigned short (&fcur)[2][8], unsigned short (&fnxt)[2][8],
    f32x4 (&acc)[6][2], int s, int m, int lr, int kg, int col,
    const unsigned short* __restrict__ legh,
    const unsigned short* __restrict__ legl,
    const unsigned short* __restrict__ fh)
{
    const int j0 = s * 32;
    half8v ah[6], al[6];
#pragma unroll
    for (int lt = 0; lt < 6; ++lt) {
        size_t o = ((size_t)m * 96 + lt * 16 + lr) * 192 + j0 + kg * 8;
        ah[lt] = *(const half8v*)&legh[o];
        al[lt] = *(const half8v*)&legl[o];
    }
    if (s + 1 < 6) {
        const int jn = (s + 1) * 32 + kg * 8;
#pragma unroll
        for (int pl = 0; pl < 2; ++pl)
#pragma unroll
            for (int i = 0; i < 8; ++i)
                fnxt[pl][i] = fh[((size_t)(jn + i) * 192 + m + 96 * pl) * NB + col];
    }
    half8v fF[2];
#pragma unroll
    for (int pl = 0; pl < 2; ++pl) {
        union { half8v h; unsigned short s16[8]; } uf;
#pragma unroll
        for (int i = 0; i < 8; ++i) uf.s16[i] = fcur[pl][i];
        fF[pl] = uf.h;
    }
#pragma unroll
    for (int lt = 0; lt < 6; ++lt)
#pragma unroll
        for (int pl = 0; pl < 2; ++pl) {
            acc[lt][pl] = __builtin_amdgcn_mfma_f32_16x16x32_f16(ah[lt], fF[pl], acc[lt][pl], 0, 0, 0);
            acc[lt][pl] = __builtin_amdgcn_mfma_f32_16x16x32_f16(al[lt], fF[pl], acc[lt][pl], 0, 0, 0);
        }
}

__global__ __launch_bounds__(256) void leg_mfma_kernel(
    const unsigned short* __restrict__ legh,  // [96 m][96 l][192 j] f16
    const unsigned short* __restrict__ legl,
    const unsigned short* __restrict__ fh,    // [192 j][192 mm][NB] f16
    unsigned int* __restrict__ out)           // [4][LMAX][MMAX][NV] packed bf16
{
    const int m   = blockIdx.x;
    const int bt  = blockIdx.y;
    const int tid = threadIdx.x;
    const int w   = tid >> 6;
    const int l   = tid & 63;
    const int lr  = l & 15;
    const int kg  = l >> 4;

    const int c  = w * 16 + lr;
    const bool cok = c < 50;
    const int col = bt * 50 + (cok ? c : 0);

    f32x4 acc[6][2];
#pragma unroll
    for (int lt = 0; lt < 6; ++lt)
#pragma unroll
        for (int pl = 0; pl < 2; ++pl) acc[lt][pl] = (f32x4){0.f, 0.f, 0.f, 0.f};

    unsigned short fA[2][8], fB[2][8];
#pragma unroll
    for (int pl = 0; pl < 2; ++pl)
#pragma unroll
        for (int i = 0; i < 8; ++i)
            fA[pl][i] = fh[((size_t)(kg * 8 + i) * 192 + m + 96 * pl) * NB + col];

#pragma unroll
    for (int ss = 0; ss < 3; ++ss) {
        k2_step(fA, fB, acc, 2 * ss,     m, lr, kg, col, legh, legl, fh);
        k2_step(fB, fA, acc, 2 * ss + 1, m, lr, kg, col, legh, legl, fh);
    }

    if (cok) {
        int B = bt * 50 + c;
        int bb = B / NV, vv = B % NV;
#pragma unroll
        for (int lt = 0; lt < 6; ++lt) {
#pragma unroll
            for (int r = 0; r < 4; ++r) {
                int ll = lt * 16 + kg * 4 + r;
                out[(((size_t)bb * LMAX + ll) * MMAX + m) * NV + vv] =
                    f2bf(acc[lt][0][r]) | (f2bf(acc[lt][1][r]) << 16);
            }
        }
    }
}

extern "C" void kernel_launch(void* const* d_in, const int* in_sizes, int n_in,
                              void* d_out, int out_size, void* d_ws, size_t ws_size,
                              hipStream_t stream) {
    if (n_in != 3) return;

    const float* data = (const float*)d_in[0];
    const unsigned int* dftw = (const unsigned int*)d_in[1];
    const float* leg  = (const float*)d_in[2];
    unsigned int* out = (unsigned int*)d_out;

    // ws: [legh][legl][At][fh]  (~53 MB total)
    const size_t LEGN = (size_t)96 * 96 * 192;
    const size_t LEGB = 2 * LEGN * sizeof(unsigned short);   // 7.08 MB
    const size_t ATN  = (size_t)43008 * 192;                 // shorts
    const size_t ATB  = ATN * sizeof(unsigned short);        // 16.5 MB
    const size_t FHB  = (size_t)192 * 192 * NB * sizeof(unsigned short); // 29.5 MB
    if (ws_size < LEGB + ATB + FHB) return;

    unsigned short* legh = (unsigned short*)d_ws;
    unsigned short* legl = legh + LEGN;
    unsigned short* At   = legl + LEGN;
    unsigned short* fh   = At + ATN;

    leg_conv_kernel<<<dim3((96 * 96 * 192 + 255) / 256), dim3(256), 0, stream>>>(
        leg, legh, legl);
    dft_transpose_kernel<<<dim3(192, 13), dim3(256), 0, stream>>>(dftw, At);

    dft_mfma_kernel<<<dim3(2400), dim3(256), 0, stream>>>(data, At, fh);
    leg_mfma_kernel<<<dim3(96, 8), dim3(256), 0, stream>>>(legh, legl, fh, out);
}